// Round 1
// baseline (776.203 us; speedup 1.0000x reference)
//
#include <hip/hip_runtime.h>

// out[i,j] = rho[i,j] if groups[i] == groups[j] else 0.
// d = 11440 (C(16,7)), fp32. Memory-bound masked copy.
//
// groups is piecewise-constant (8 contiguous segments: photon count at mode 0
// from 7 down to 0), so the mask is block-diagonal, ~40% dense. We read the
// 4 column-group values first and skip the rho load entirely when no column
// in the quad matches the row group — saving ~60% of read traffic. The
// branch is wave-uniform except at segment boundaries (8 boundaries out of
// 2860 quads/row), so divergence is negligible.
//
// Row index comes from blockIdx.y => groups[row] compiles to a scalar
// (s_load) broadcast. Column loads are int4/float4 (16 B/lane, coalesced).

__global__ __launch_bounds__(256) void pvm_mask_kernel(
    const float* __restrict__ rho,
    const int* __restrict__ groups,
    float* __restrict__ out,
    int d /* must be divisible by 4; 11440 is */) {

    const int n4  = d >> 2;                       // float4s per row
    const int c4  = blockIdx.x * blockDim.x + threadIdx.x;
    if (c4 >= n4) return;

    const int row = blockIdx.y;
    const int gi  = groups[row];                  // block-uniform -> SGPR

    const int4 g = ((const int4*)groups)[c4];

    const long long q = (long long)row * n4 + c4; // float4 index, fits 64b

    float4 v = make_float4(0.f, 0.f, 0.f, 0.f);
    const bool m0 = (g.x == gi);
    const bool m1 = (g.y == gi);
    const bool m2 = (g.z == gi);
    const bool m3 = (g.w == gi);

    if (m0 | m1 | m2 | m3) {
        const float4 r = ((const float4*)rho)[q];
        v.x = m0 ? r.x : 0.f;
        v.y = m1 ? r.y : 0.f;
        v.z = m2 ? r.z : 0.f;
        v.w = m3 ? r.w : 0.f;
    }

    ((float4*)out)[q] = v;
}

extern "C" void kernel_launch(void* const* d_in, const int* in_sizes, int n_in,
                              void* d_out, int out_size, void* d_ws, size_t ws_size,
                              hipStream_t stream) {
    const float* rho    = (const float*)d_in[0];
    const int*   groups = (const int*)d_in[1];
    float*       out    = (float*)d_out;

    const int d  = in_sizes[1];    // 11440
    const int n4 = d >> 2;         // 2860

    dim3 block(256, 1, 1);
    dim3 grid((n4 + 255) / 256, d, 1);
    pvm_mask_kernel<<<grid, block, 0, stream>>>(rho, groups, out, d);
}

// Round 2
// 749.202 us; speedup vs baseline: 1.0360x; 1.0360x over previous
//
#include <hip/hip_runtime.h>

// out[i,j] = rho[i,j] if groups[i] == groups[j] else 0.   d = 11440, fp32.
//
// groups (photon count at mode 0) is sorted DESCENDING by construction of the
// basis enumeration: 8 contiguous segments of sizes 1,9,45,165,495,1287,3003,
// 6435. So for each row the kept columns are ONE contiguous interval
// [seg_lo, seg_hi). Per block (= per row) we binary-search that interval once
// (L1-cached broadcast loads), then run three branch-free block-uniform loops:
//   - zero-store outside the interval (no rho reads at all -> saves 60% of
//     read traffic; total HBM = 523 MB write + ~210 MB read)
//   - float4 copy strictly inside
//   - <=2 boundary quads handled elementwise.
// One block per row, ~11 quads/thread grid-stride => enough outstanding
// loads/stores to hide HBM latency (R1's one-quad-per-thread with a
// branch-dependent load was latency-bound).

__global__ __launch_bounds__(256) void pvm_mask_kernel(
    const float* __restrict__ rho,
    const int* __restrict__ groups,
    float* __restrict__ out,
    int d /* divisible by 4 */) {

    const int row = blockIdx.x;
    const int tid = threadIdx.x;
    const int n4  = d >> 2;
    const int gi  = groups[row];

    // groups sorted descending: find [seg_lo, seg_hi) with groups[j] == gi.
    int lo = 0, hi = d;
    while (lo < hi) { int m = (lo + hi) >> 1; if (groups[m] > gi) lo = m + 1; else hi = m; }
    const int seg_lo = lo;
    hi = d;                       // lo already >= seg_lo
    while (lo < hi) { int m = (lo + hi) >> 1; if (groups[m] >= gi) lo = m + 1; else hi = m; }
    const int seg_hi = lo;        // one past last match

    const size_t base = (size_t)row * (size_t)d;
    const float4* __restrict__ rin  = (const float4*)(rho + base);
    float4*       __restrict__ rout = (float4*)(out + base);

    const int q_lo = seg_lo >> 2;        // quad containing seg_lo
    const int qa   = (seg_lo + 3) >> 2;  // first fully-inside quad
    const int qb   = seg_hi >> 2;        // one past last fully-inside quad
    const int q_hi = (seg_hi + 3) >> 2;  // one past last touched quad

    const float4 z = make_float4(0.f, 0.f, 0.f, 0.f);

    // leading zeros [0, q_lo)
    #pragma unroll 4
    for (int q = tid; q < q_lo; q += 256) rout[q] = z;

    // trailing zeros [q_hi, n4)
    #pragma unroll 4
    for (int q = q_hi + tid; q < n4; q += 256) rout[q] = z;

    // interior pure copy [qa, qb)
    #pragma unroll 4
    for (int q = qa + tid; q < qb; q += 256) rout[q] = rin[q];

    // boundary partial quads (at most 2 per row), elementwise masked
    if (qa > q_lo && tid < 4) {
        const int j = (q_lo << 2) + tid;
        const float v = (j >= seg_lo && j < seg_hi) ? rho[base + j] : 0.f;
        out[base + j] = v;
    }
    if (qb >= qa && q_hi > qb && tid >= 4 && tid < 8) {
        const int j = (qb << 2) + (tid - 4);
        const float v = (j >= seg_lo && j < seg_hi) ? rho[base + j] : 0.f;
        out[base + j] = v;
    }
}

extern "C" void kernel_launch(void* const* d_in, const int* in_sizes, int n_in,
                              void* d_out, int out_size, void* d_ws, size_t ws_size,
                              hipStream_t stream) {
    const float* rho    = (const float*)d_in[0];
    const int*   groups = (const int*)d_in[1];
    float*       out    = (float*)d_out;

    const int d = in_sizes[1];   // 11440

    dim3 block(256, 1, 1);
    dim3 grid(d, 1, 1);          // one block per row
    pvm_mask_kernel<<<grid, block, 0, stream>>>(rho, groups, out, d);
}